// Round 3
// baseline (983.670 us; speedup 1.0000x reference)
//
#include <hip/hip_runtime.h>
#include <hip/hip_bf16.h>
#include <cstdint>
#include <cstddef>

// Problem constants (match reference)
#define BB 16
#define SS 384
#define GG 384
#define NN 768          // S + G
#define DD 128
#define EC 100
#define TT 21
#define NHEADS 4
#define BN (BB*NN)      // 12288
#define BS (BB*SS)      // 6144

typedef float v2f __attribute__((ext_vector_type(2)));

__device__ __forceinline__ float sigf(float x) { return 1.0f / (1.0f + __expf(-x)); }
__device__ __forceinline__ float tanh_fast(float x) {
    // 1 - 2/(exp(2x)+1); exp overflow -> inf -> 1, underflow -> 0 -> -1
    return 1.0f - 2.0f / (__expf(2.0f * x) + 1.0f);
}
__device__ __forceinline__ float wred_max(float v) {
    #pragma unroll
    for (int o = 32; o > 0; o >>= 1) v = fmaxf(v, __shfl_xor(v, o));
    return v;
}
__device__ __forceinline__ float wred_sum(float v) {
    #pragma unroll
    for (int o = 32; o > 0; o >>= 1) v += __shfl_xor(v, o);
    return v;
}

// ---------------------------------------------------------------------------
// xw = emb @ w_ih^T + b for both directions.  Tiled GEMM with char gather.
// grid (96 row-tiles, 8): blockIdx.y -> dir(2) x gate-tile(4).  64x64 tiles.
// ---------------------------------------------------------------------------
__global__ __launch_bounds__(256) void k_xw(
    const int* __restrict__ batch_char, const float* __restrict__ char_table,
    const float* __restrict__ w_ih_f, const float* __restrict__ b_f,
    const float* __restrict__ w_ih_b, const float* __restrict__ b_b,
    float* __restrict__ xw_f, float* __restrict__ xw_b)
{
    __shared__ float At[EC * 68];   // [e][row]
    __shared__ float Bt[EC * 68];   // [e][gate]
    __shared__ int   chs[64];
    const int tid = threadIdx.x;
    const int rt  = blockIdx.x;             // row tile (64 rows of B*S)
    const int ot  = blockIdx.y;             // dir*4 + gate tile
    const int dir = ot >> 2, gt = ot & 3;
    const float* wih  = dir ? w_ih_b : w_ih_f;
    const float* bias = dir ? b_b    : b_f;
    float*       out  = dir ? xw_b   : xw_f;

    if (tid < 64) chs[tid] = batch_char[rt * 64 + tid];
    __syncthreads();
    for (int idx = tid; idx < 64 * EC; idx += 256) {
        int r = idx / EC, e = idx - r * EC;
        At[e * 68 + r] = char_table[(size_t)chs[r] * EC + e];
        Bt[e * 68 + r] = wih[(size_t)(gt * 64 + r) * EC + e];
    }
    __syncthreads();

    const int ty = tid >> 4, tx = tid & 15;
    const int r0 = ty * 4, c0 = tx * 4;
    float acc[4][4] = {};
    #pragma unroll 4
    for (int e = 0; e < EC; ++e) {
        float4 a = *(const float4*)&At[e * 68 + r0];
        float4 bv = *(const float4*)&Bt[e * 68 + c0];
        float av[4] = {a.x, a.y, a.z, a.w};
        float bb[4] = {bv.x, bv.y, bv.z, bv.w};
        #pragma unroll
        for (int i = 0; i < 4; ++i)
            #pragma unroll
            for (int j = 0; j < 4; ++j) acc[i][j] = fmaf(av[i], bb[j], acc[i][j]);
    }
    #pragma unroll
    for (int i = 0; i < 4; ++i) {
        int row = rt * 64 + r0 + i;
        int gc  = gt * 64 + c0;
        float4 o;
        o.x = acc[i][0] + bias[gc + 0];
        o.y = acc[i][1] + bias[gc + 1];
        o.z = acc[i][2] + bias[gc + 2];
        o.w = acc[i][3] + bias[gc + 3];
        *(float4*)&out[(size_t)row * 256 + gc] = o;
    }
}

// ---------------------------------------------------------------------------
// gaz embedding gather into gat_in rows [S, N)
// ---------------------------------------------------------------------------
__global__ __launch_bounds__(256) void k_gaz(
    const int* __restrict__ gaz_list, const float* __restrict__ gaz_table,
    float* __restrict__ gat_in)
{
    int idx = blockIdx.x * 256 + threadIdx.x;      // B*G*128 total
    int d = idx & 127;
    int rest = idx >> 7;
    int g = rest % GG;
    int b = rest / GG;
    float v = gaz_table[(size_t)gaz_list[b * GG + g] * DD + d];
    gat_in[((size_t)b * NN + SS + g) * DD + d] = v;
}

// ---------------------------------------------------------------------------
// BiLSTM scan.  grid 32 = (batch, dir).  256 threads = 256 gates.
// h broadcast via per-wave LDS copy (hbuf[wave]) read with wave-uniform
// ds_read_b128 (broadcast, conflict-free, in-order within wave -> no extra
// barrier).  No v_readlane (VALU->SGPR hazard stalls).  Matvec as 32
// v_pk_fma_f32.  One barrier/step for the pre[] gate exchange (dbuf'd).
// ---------------------------------------------------------------------------
__global__ __launch_bounds__(256) void k_lstm(
    const float* __restrict__ xw_f, const float* __restrict__ xw_b,
    const float* __restrict__ w_hh_f, const float* __restrict__ w_hh_b,
    float* __restrict__ gat_in)
{
    __shared__ float pre[2][256];
    __shared__ float hbuf[4][64];           // per-wave private copy of h
    const int tid = threadIdx.x, wave = tid >> 6, lane = tid & 63;
    const int b = blockIdx.x >> 1, dir = blockIdx.x & 1;
    const float* xw = (dir ? xw_b : xw_f) + (size_t)b * SS * 256;
    const float* wrow = (dir ? w_hh_b : w_hh_f) + (size_t)tid * 64;
    v2f w2[32];
    #pragma unroll
    for (int q = 0; q < 16; ++q) {
        float4 v = *(const float4*)&wrow[q * 4];
        w2[2 * q + 0] = v2f{v.x, v.y};
        w2[2 * q + 1] = v2f{v.z, v.w};
    }
    hbuf[wave][lane] = 0.f;                 // own-wave copy; in-order LDS
    float c = 0.f;
    int buf = 0;
    float xv = xw[(dir ? (SS - 1) : 0) * 256 + tid];
    const float4* h4 = (const float4*)hbuf[wave];
    for (int tt = 0; tt < SS; ++tt) {
        const int t = dir ? (SS - 1 - tt) : tt;
        const int tn = dir ? (t - 1) : (t + 1);
        float xnext = (tt + 1 < SS) ? xw[tn * 256 + tid] : 0.f;   // prefetch
        v2f a0 = {0.f, 0.f}, a1 = {0.f, 0.f}, a2 = {0.f, 0.f}, a3 = {0.f, 0.f};
        #pragma unroll
        for (int q = 0; q < 16; q += 2) {
            float4 ha = h4[q];
            float4 hb = h4[q + 1];
            a0 = __builtin_elementwise_fma(v2f{ha.x, ha.y}, w2[2 * q + 0], a0);
            a1 = __builtin_elementwise_fma(v2f{ha.z, ha.w}, w2[2 * q + 1], a1);
            a2 = __builtin_elementwise_fma(v2f{hb.x, hb.y}, w2[2 * q + 2], a2);
            a3 = __builtin_elementwise_fma(v2f{hb.z, hb.w}, w2[2 * q + 3], a3);
        }
        v2f s = (a0 + a1) + (a2 + a3);
        pre[buf][tid] = xv + s.x + s.y;
        __syncthreads();
        float gi = pre[buf][lane];
        float gf = pre[buf][64 + lane];
        float gg = pre[buf][128 + lane];
        float go = pre[buf][192 + lane];
        float nc = sigf(gf) * c + sigf(gi) * tanh_fast(gg);
        float nh = sigf(go) * tanh_fast(nc);
        c = nc;
        hbuf[wave][lane] = nh;              // own-wave copy; read next step
        if (wave == 0) gat_in[((size_t)b * NN + t) * DD + dir * 64 + lane] = nh;
        xv = xnext;
        buf ^= 1;
    }
}

// ---------------------------------------------------------------------------
// GAT layer-1 projection: h1 = gat_in @ Wh[k][hd] (+ per-row f1/f2 dots).
// grid (192 row-tiles, 4 heads).  64x64 tile, K=128 in 2 phases of 64.
// ---------------------------------------------------------------------------
__global__ __launch_bounds__(256) void k_p1(
    const float* __restrict__ gat_in, const float* __restrict__ gat_Wh,
    const float* __restrict__ gat_ah, int k,
    float* __restrict__ h1, float* __restrict__ f1g, float* __restrict__ f2g)
{
    __shared__ float At[64 * 68];
    __shared__ float Bt[64 * 68];
    __shared__ float sf1[64], sf2[64];
    const int tid = threadIdx.x;
    const int rt = blockIdx.x, hd = blockIdx.y;
    if (tid < 64) { sf1[tid] = 0.f; sf2[tid] = 0.f; }
    const float* W = gat_Wh + ((size_t)(k * NHEADS + hd)) * DD * 64;
    const int ty = tid >> 4, tx = tid & 15;
    const int r0 = ty * 4, c0 = tx * 4;
    float acc[4][4] = {};
    for (int ph = 0; ph < 2; ++ph) {
        __syncthreads();
        for (int idx = tid; idx < 64 * 64; idx += 256) {
            int r = idx >> 6, e = idx & 63;
            At[e * 68 + r] = gat_in[((size_t)(rt * 64 + r)) * DD + ph * 64 + e];
            Bt[e * 68 + r] = W[(size_t)(ph * 64 + e) * 64 + r];
        }
        __syncthreads();
        #pragma unroll 4
        for (int e = 0; e < 64; ++e) {
            float4 a = *(const float4*)&At[e * 68 + r0];
            float4 bv = *(const float4*)&Bt[e * 68 + c0];
            float av[4] = {a.x, a.y, a.z, a.w};
            float bb[4] = {bv.x, bv.y, bv.z, bv.w};
            #pragma unroll
            for (int i = 0; i < 4; ++i)
                #pragma unroll
                for (int j = 0; j < 4; ++j) acc[i][j] = fmaf(av[i], bb[j], acc[i][j]);
        }
    }
    const float* ah = gat_ah + (size_t)(k * NHEADS + hd) * 128;
    float a1[4], a2[4];
    #pragma unroll
    for (int j = 0; j < 4; ++j) { a1[j] = ah[c0 + j]; a2[j] = ah[64 + c0 + j]; }
    #pragma unroll
    for (int i = 0; i < 4; ++i) {
        int n = rt * 64 + r0 + i;
        float4 o = make_float4(acc[i][0], acc[i][1], acc[i][2], acc[i][3]);
        *(float4*)&h1[((size_t)n * NHEADS + hd) * 64 + c0] = o;
        float p1 = acc[i][0] * a1[0] + acc[i][1] * a1[1] + acc[i][2] * a1[2] + acc[i][3] * a1[3];
        float p2 = acc[i][0] * a2[0] + acc[i][1] * a2[1] + acc[i][2] * a2[2] + acc[i][3] * a2[3];
        atomicAdd(&sf1[r0 + i], p1);
        atomicAdd(&sf2[r0 + i], p2);
    }
    __syncthreads();
    if (tid < 64) {
        f1g[hd * BN + rt * 64 + tid] = sf1[tid];
        f2g[hd * BN + rt * 64 + tid] = sf2[tid];
    }
}

// ---------------------------------------------------------------------------
// GAT layer-1 attention (sparse).  One block per row n=(b,i); wave = head.
// Ballot-based neighbor compaction (no LDS atomics); 4-acc gather.
// Also emits bit-packed adjacency for layer 2.
// ---------------------------------------------------------------------------
__global__ __launch_bounds__(256) void k_attn1(
    const int* __restrict__ adj, const float* __restrict__ h1,
    const float* __restrict__ f1g, const float* __restrict__ f2g,
    float* __restrict__ out1, unsigned long long* __restrict__ packed)
{
    __shared__ int   nbr[NN];
    __shared__ float ep[NHEADS][NN];
    __shared__ unsigned long long wm[12];
    __shared__ int cntS;
    const int tid = threadIdx.x, wave = tid >> 6, lane = tid & 63;
    const int n = blockIdx.x;
    const int b = n / NN;
    #pragma unroll
    for (int it = 0; it < 3; ++it) {
        int j = it * 256 + tid;
        int a = adj[(size_t)n * NN + j];
        unsigned long long m = __ballot(a > 0);
        if (lane == 0) { wm[it * 4 + wave] = m; packed[(size_t)n * 12 + it * 4 + wave] = m; }
    }
    __syncthreads();
    if (wave == 0) {
        unsigned long long m = (lane < 12) ? wm[lane] : 0ULL;
        int pc = __popcll(m);
        int inc = pc;
        #pragma unroll
        for (int d = 1; d < 16; d <<= 1) { int t = __shfl_up(inc, d); if (lane >= d) inc += t; }
        int C = __shfl(inc, 11);
        if (lane == 0) cntS = C;
        int off = inc - pc;
        while (m) {
            int bit = __builtin_ctzll(m);
            nbr[off++] = lane * 64 + bit;
            m &= m - 1;
        }
    }
    __syncthreads();
    const int C = cntS;
    const int hd = wave;
    const float f1 = f1g[hd * BN + n];
    const float* f2p = f2g + hd * BN + b * NN;
    float mx = -3.0e38f;
    for (int t = lane; t < C; t += 64) {
        float e = f1 + f2p[nbr[t]];
        e = (e >= 0.f) ? e : 0.2f * e;
        ep[hd][t] = e;
        mx = fmaxf(mx, e);
    }
    mx = wred_max(mx);
    float sum = 0.f;
    for (int t = lane; t < C; t += 64) {
        float p = __expf(ep[hd][t] - mx);
        ep[hd][t] = p;
        sum += p;
    }
    sum = wred_sum(sum);
    const float* hb = h1 + (size_t)b * NN * (NHEADS * 64) + hd * 64 + lane;
    float ac0 = 0.f, ac1 = 0.f, ac2 = 0.f, ac3 = 0.f;
    int t = 0;
    for (; t + 3 < C; t += 4) {
        int j0 = nbr[t], j1 = nbr[t + 1], j2 = nbr[t + 2], j3 = nbr[t + 3];
        float p0 = ep[hd][t], p1 = ep[hd][t + 1], p2 = ep[hd][t + 2], p3 = ep[hd][t + 3];
        ac0 = fmaf(p0, hb[(size_t)j0 * 256], ac0);
        ac1 = fmaf(p1, hb[(size_t)j1 * 256], ac1);
        ac2 = fmaf(p2, hb[(size_t)j2 * 256], ac2);
        ac3 = fmaf(p3, hb[(size_t)j3 * 256], ac3);
    }
    for (; t < C; ++t) ac0 = fmaf(ep[hd][t], hb[(size_t)nbr[t] * 256], ac0);
    float r = ((ac0 + ac1) + (ac2 + ac3)) / sum;
    r = (r > 0.f) ? r : expm1f(r);
    out1[(size_t)n * 256 + hd * 64 + lane] = r;
}

// ---------------------------------------------------------------------------
// Output-layer projection: h2 = out1 @ Wo[k]  (+ f1o/f2o dots).  12 rows/block.
// ---------------------------------------------------------------------------
__global__ __launch_bounds__(256) void k_p2(
    const float* __restrict__ out1, const float* __restrict__ gat_Wo,
    const float* __restrict__ gat_ao, int k,
    float* __restrict__ h2, float* __restrict__ f1o, float* __restrict__ f2o)
{
    __shared__ float ld[12 * 256];
    __shared__ float lf1[12], lf2[12];
    const int tid = threadIdx.x;
    const int blk = blockIdx.x;
    if (tid < 12) { lf1[tid] = 0.f; lf2[tid] = 0.f; }
    for (int idx = tid; idx < 12 * 256; idx += 256)
        ld[idx] = out1[(size_t)blk * 12 * 256 + idx];
    __syncthreads();
    if (tid < 252) {
        const int r = tid / TT, c = tid - r * TT;
        const float* Wo = gat_Wo + (size_t)k * 256 * TT;
        const float4* row4 = (const float4*)&ld[r * 256];
        float acc = 0.f;
        #pragma unroll 8
        for (int q4 = 0; q4 < 64; ++q4) {
            float4 v = row4[q4];
            int q = q4 * 4;
            acc = fmaf(v.x, Wo[(q + 0) * TT + c], acc);
            acc = fmaf(v.y, Wo[(q + 1) * TT + c], acc);
            acc = fmaf(v.z, Wo[(q + 2) * TT + c], acc);
            acc = fmaf(v.w, Wo[(q + 3) * TT + c], acc);
        }
        const int n = blk * 12 + r;
        h2[(size_t)n * TT + c] = acc;
        const float* ao = gat_ao + k * 2 * TT;
        atomicAdd(&lf1[r], acc * ao[c]);
        atomicAdd(&lf2[r], acc * ao[TT + c]);
    }
    __syncthreads();
    if (tid < 12) {
        f1o[blk * 12 + tid] = lf1[tid];
        f2o[blk * 12 + tid] = lf2[tid];
    }
}

// ---------------------------------------------------------------------------
// Output-layer attention + elu.  One wave per (b, s<S).  Neighbor lists are
// rebuilt from the bit-packed adjacency written by k_attn1.
// ---------------------------------------------------------------------------
__global__ __launch_bounds__(64) void k_attn2(
    const unsigned long long* __restrict__ packed,
    const float* __restrict__ h2, const float* __restrict__ f1o,
    const float* __restrict__ f2o, float* __restrict__ out2k)
{
    __shared__ int   nbr[NN];
    __shared__ float ep[NN];
    const int lane = threadIdx.x;
    const int blk = blockIdx.x;                 // b*S + s
    const int b = blk / SS, s = blk - b * SS;
    const int n = b * NN + s;
    unsigned long long w64 = (lane < 12) ? packed[(size_t)n * 12 + lane] : 0ULL;
    int pc = __popcll(w64);
    int inc = pc;
    #pragma unroll
    for (int d = 1; d < 16; d <<= 1) {
        int t = __shfl_up(inc, d, 16);
        if ((lane & 15) >= d) inc += t;
    }
    const int C = __shfl(inc, 11);
    int off = inc - pc;
    while (w64) {
        int bit = __builtin_ctzll(w64);
        nbr[off++] = lane * 64 + bit;
        w64 &= w64 - 1;
    }
    __syncthreads();
    const float f1 = f1o[n];
    const float* f2p = f2o + b * NN;
    float mx = -3.0e38f;
    for (int t = lane; t < C; t += 64) {
        int j = nbr[t];
        float e = f1 + f2p[j];
        e = (e >= 0.f) ? e : 0.2f * e;
        ep[t] = e;
        mx = fmaxf(mx, e);
    }
    mx = wred_max(mx);
    float sum = 0.f;
    for (int t = lane; t < C; t += 64) {
        float p = __expf(ep[t] - mx);
        ep[t] = p;
        sum += p;
    }
    sum = wred_sum(sum);
    const float* h2b = h2 + (size_t)b * NN * TT + ((lane < TT) ? lane : 0);
    float ac0 = 0.f, ac1 = 0.f, ac2 = 0.f, ac3 = 0.f;
    int t = 0;
    for (; t + 3 < C; t += 4) {
        int j0 = nbr[t], j1 = nbr[t + 1], j2 = nbr[t + 2], j3 = nbr[t + 3];
        float p0 = ep[t], p1 = ep[t + 1], p2 = ep[t + 2], p3 = ep[t + 3];
        ac0 = fmaf(p0, h2b[(size_t)j0 * TT], ac0);
        ac1 = fmaf(p1, h2b[(size_t)j1 * TT], ac1);
        ac2 = fmaf(p2, h2b[(size_t)j2 * TT], ac2);
        ac3 = fmaf(p3, h2b[(size_t)j3 * TT], ac3);
    }
    for (; t < C; ++t) ac0 = fmaf(ep[t], h2b[(size_t)nbr[t] * TT], ac0);
    if (lane < TT) {
        float r = ((ac0 + ac1) + (ac2 + ac3)) / sum;
        r = (r > 0.f) ? r : expm1f(r);
        out2k[(size_t)blk * TT + lane] = r;
    }
}

// ---------------------------------------------------------------------------
// feats = fuse_w[0]*(lstm_feat@h2h_W^T + b) + sum_k fuse_w[k+1]*out2_k
// ---------------------------------------------------------------------------
__global__ __launch_bounds__(64) void k_fuse(
    const float* __restrict__ gat_in, const float* __restrict__ h2h_W,
    const float* __restrict__ h2h_b, const float* __restrict__ fuse_w,
    const float* __restrict__ out2, float* __restrict__ feats)
{
    __shared__ float row[DD];
    const int lane = threadIdx.x;
    const int blk = blockIdx.x;                 // b*S + s
    const int b = blk / SS, s = blk - b * SS;
    const float* src = gat_in + ((size_t)b * NN + s) * DD;
    row[lane] = src[lane];
    row[lane + 64] = src[lane + 64];
    __syncthreads();
    if (lane < TT) {
        float acc = h2h_b[lane];
        const float4* w4 = (const float4*)&h2h_W[lane * DD];
        const float4* r4 = (const float4*)row;
        #pragma unroll 8
        for (int d4 = 0; d4 < 32; ++d4) {
            float4 w = w4[d4]; float4 v = r4[d4];
            acc = fmaf(w.x, v.x, acc); acc = fmaf(w.y, v.y, acc);
            acc = fmaf(w.z, v.z, acc); acc = fmaf(w.w, v.w, acc);
        }
        size_t o = (size_t)blk * TT + lane;
        feats[o] = fuse_w[0] * acc + fuse_w[1] * out2[o]
                 + fuse_w[2] * out2[(size_t)BS * TT + o]
                 + fuse_w[3] * out2[2 * (size_t)BS * TT + o];
    }
}

// ---------------------------------------------------------------------------
// Viterbi decode.  One wave per batch.  Lanes = (p-group 0..2) x (c 0..20).
// ---------------------------------------------------------------------------
__global__ __launch_bounds__(64) void k_vit(
    const float* __restrict__ feats, const float* __restrict__ trans,
    int* __restrict__ out)
{
    __shared__ float part[24];
    __shared__ unsigned char bp[SS - 1][24];
    const int lane = threadIdx.x;
    const int b = blockIdx.x;
    const int pg = lane / TT;                 // 0,1,2 (lane 63 idle)
    const int c = lane - pg * TT;
    const bool act = (pg < 3);
    const int p0 = pg * 7;
    float tc[7];
    if (act) {
        #pragma unroll
        for (int u = 0; u < 7; ++u) tc[u] = trans[(p0 + u) * TT + c];
    }
    if (lane < TT) part[lane] = feats[((size_t)b * SS) * TT + lane] + trans[19 * TT + lane];
    if (lane >= TT && lane < 24) part[lane] = -3.0e38f;
    __syncthreads();
    for (int t = 1; t < SS; ++t) {
        float best = -3.0e38f; int bi = 0;
        if (act) {
            #pragma unroll
            for (int u = 0; u < 7; ++u) {
                float v = part[p0 + u] + tc[u];
                if (v > best) { best = v; bi = p0 + u; }
            }
        }
        float bv1 = __shfl(best, lane + 21);
        int   bi1 = __shfl(bi,   lane + 21);
        float bv2 = __shfl(best, lane + 42);
        int   bi2 = __shfl(bi,   lane + 42);
        if (lane < TT) {
            if (bv1 > best) { best = bv1; bi = bi1; }
            if (bv2 > best) { best = bv2; bi = bi2; }
            bp[t - 1][lane] = (unsigned char)bi;
            part[lane] = best + feats[((size_t)b * SS + t) * TT + lane];
        }
        __syncthreads();
    }
    float fv = (lane < TT) ? part[lane] + trans[lane * TT + 20] : -3.0e38f;
    int fi = (lane < TT) ? lane : 0;
    #pragma unroll
    for (int o = 32; o > 0; o >>= 1) {
        float ov = __shfl_xor(fv, o);
        int oi = __shfl_xor(fi, o);
        if (ov > fv || (ov == fv && oi < fi)) { fv = ov; fi = oi; }
    }
    __syncthreads();
    if (lane == 0) {
        int cur = fi;
        out[b * SS + SS - 1] = cur;
        for (int u = SS - 2; u >= 0; --u) {
            cur = bp[u][cur];
            out[b * SS + u] = cur;
        }
    }
}

// ---------------------------------------------------------------------------
extern "C" void kernel_launch(void* const* d_in, const int* in_sizes, int n_in,
                              void* d_out, int out_size, void* d_ws, size_t ws_size,
                              hipStream_t stream) {
    (void)in_sizes; (void)n_in; (void)out_size; (void)ws_size;
    const int*   batch_char = (const int*)d_in[0];
    const int*   gaz_list   = (const int*)d_in[2];
    const int*   graphs[3]  = {(const int*)d_in[3], (const int*)d_in[4], (const int*)d_in[5]};
    const float* char_table = (const float*)d_in[7];
    const float* gaz_table  = (const float*)d_in[8];
    const float* w_ih_f = (const float*)d_in[9];
    const float* w_hh_f = (const float*)d_in[10];
    const float* b_f    = (const float*)d_in[11];
    const float* w_ih_b = (const float*)d_in[12];
    const float* w_hh_b = (const float*)d_in[13];
    const float* b_b    = (const float*)d_in[14];
    const float* h2h_W  = (const float*)d_in[15];
    const float* h2h_b  = (const float*)d_in[16];
    const float* gat_Wh = (const float*)d_in[17];
    const float* gat_ah = (const float*)d_in[18];
    const float* gat_Wo = (const float*)d_in[19];
    const float* gat_ao = (const float*)d_in[20];
    const float* fuse_w = (const float*)d_in[21];
    const float* trans  = (const float*)d_in[22];

    float* ws = (float*)d_ws;
    float* gat_in = ws;                         // 1,572,864
    float* xw_f   = gat_in + 1572864;           // 1,572,864
    float* xw_b   = xw_f   + 1572864;           // 1,572,864
    float* h1     = xw_b   + 1572864;           // 3,145,728
    float* out1   = h1     + 3145728;           // 3,145,728
    float* h2     = out1   + 3145728;           //   258,048
    float* f1g    = h2     + 258048;            //    49,152
    float* f2g    = f1g    + 49152;             //    49,152
    float* f1o    = f2g    + 49152;             //    12,288
    float* f2o    = f1o    + 12288;             //    12,288
    float* out2   = f2o    + 12288;             //   387,072
    float* feats  = out2   + 387072;            //   129,024
    unsigned long long* packed = (unsigned long long*)(feats + 129024);  // 98,304 u64

    k_xw<<<dim3(96, 8), 256, 0, stream>>>(batch_char, char_table, w_ih_f, b_f,
                                          w_ih_b, b_b, xw_f, xw_b);
    k_gaz<<<3072, 256, 0, stream>>>(gaz_list, gaz_table, gat_in);
    k_lstm<<<32, 256, 0, stream>>>(xw_f, xw_b, w_hh_f, w_hh_b, gat_in);
    for (int k = 0; k < 3; ++k) {
        k_p1<<<dim3(192, 4), 256, 0, stream>>>(gat_in, gat_Wh, gat_ah, k, h1, f1g, f2g);
        k_attn1<<<BN, 256, 0, stream>>>(graphs[k], h1, f1g, f2g, out1, packed);
        k_p2<<<1024, 256, 0, stream>>>(out1, gat_Wo, gat_ao, k, h2, f1o, f2o);
        k_attn2<<<BS, 64, 0, stream>>>(packed, h2, f1o, f2o, out2 + (size_t)k * BS * TT);
    }
    k_fuse<<<BS, 64, 0, stream>>>(gat_in, h2h_W, h2h_b, fuse_w, out2, feats);
    k_vit<<<BB, 64, 0, stream>>>(feats, trans, (int*)d_out);
}

// Round 4
// 949.298 us; speedup vs baseline: 1.0362x; 1.0362x over previous
//
#include <hip/hip_runtime.h>
#include <hip/hip_bf16.h>
#include <cstdint>
#include <cstddef>

// Problem constants (match reference)
#define BB 16
#define SS 384
#define GG 384
#define NN 768          // S + G
#define DD 128
#define EC 100
#define TT 21
#define NHEADS 4
#define BN (BB*NN)      // 12288
#define BS (BB*SS)      // 6144

typedef float v2f __attribute__((ext_vector_type(2)));

__device__ __forceinline__ float sigf(float x) { return 1.0f / (1.0f + __expf(-x)); }
__device__ __forceinline__ float tanh_fast(float x) {
    // 1 - 2/(exp(2x)+1); exp overflow -> inf -> 1, underflow -> 0 -> -1
    return 1.0f - 2.0f / (__expf(2.0f * x) + 1.0f);
}
__device__ __forceinline__ float wred_max(float v) {
    #pragma unroll
    for (int o = 32; o > 0; o >>= 1) v = fmaxf(v, __shfl_xor(v, o));
    return v;
}
__device__ __forceinline__ float wred_sum(float v) {
    #pragma unroll
    for (int o = 32; o > 0; o >>= 1) v += __shfl_xor(v, o);
    return v;
}

// ---------------------------------------------------------------------------
// xw = emb @ w_ih^T + b for both directions.  Tiled GEMM with char gather.
// grid (96 row-tiles, 8): blockIdx.y -> dir(2) x gate-tile(4).  64x64 tiles.
// ---------------------------------------------------------------------------
__global__ __launch_bounds__(256) void k_xw(
    const int* __restrict__ batch_char, const float* __restrict__ char_table,
    const float* __restrict__ w_ih_f, const float* __restrict__ b_f,
    const float* __restrict__ w_ih_b, const float* __restrict__ b_b,
    float* __restrict__ xw_f, float* __restrict__ xw_b)
{
    __shared__ float At[EC * 68];   // [e][row]
    __shared__ float Bt[EC * 68];   // [e][gate]
    __shared__ int   chs[64];
    const int tid = threadIdx.x;
    const int rt  = blockIdx.x;             // row tile (64 rows of B*S)
    const int ot  = blockIdx.y;             // dir*4 + gate tile
    const int dir = ot >> 2, gt = ot & 3;
    const float* wih  = dir ? w_ih_b : w_ih_f;
    const float* bias = dir ? b_b    : b_f;
    float*       out  = dir ? xw_b   : xw_f;

    if (tid < 64) chs[tid] = batch_char[rt * 64 + tid];
    __syncthreads();
    for (int idx = tid; idx < 64 * EC; idx += 256) {
        int r = idx / EC, e = idx - r * EC;
        At[e * 68 + r] = char_table[(size_t)chs[r] * EC + e];
        Bt[e * 68 + r] = wih[(size_t)(gt * 64 + r) * EC + e];
    }
    __syncthreads();

    const int ty = tid >> 4, tx = tid & 15;
    const int r0 = ty * 4, c0 = tx * 4;
    float acc[4][4] = {};
    #pragma unroll 4
    for (int e = 0; e < EC; ++e) {
        float4 a = *(const float4*)&At[e * 68 + r0];
        float4 bv = *(const float4*)&Bt[e * 68 + c0];
        float av[4] = {a.x, a.y, a.z, a.w};
        float bb[4] = {bv.x, bv.y, bv.z, bv.w};
        #pragma unroll
        for (int i = 0; i < 4; ++i)
            #pragma unroll
            for (int j = 0; j < 4; ++j) acc[i][j] = fmaf(av[i], bb[j], acc[i][j]);
    }
    #pragma unroll
    for (int i = 0; i < 4; ++i) {
        int row = rt * 64 + r0 + i;
        int gc  = gt * 64 + c0;
        float4 o;
        o.x = acc[i][0] + bias[gc + 0];
        o.y = acc[i][1] + bias[gc + 1];
        o.z = acc[i][2] + bias[gc + 2];
        o.w = acc[i][3] + bias[gc + 3];
        *(float4*)&out[(size_t)row * 256 + gc] = o;
    }
}

// ---------------------------------------------------------------------------
// gaz embedding gather into gat_in rows [S, N)
// ---------------------------------------------------------------------------
__global__ __launch_bounds__(256) void k_gaz(
    const int* __restrict__ gaz_list, const float* __restrict__ gaz_table,
    float* __restrict__ gat_in)
{
    int idx = blockIdx.x * 256 + threadIdx.x;      // B*G*128 total
    int d = idx & 127;
    int rest = idx >> 7;
    int g = rest % GG;
    int b = rest / GG;
    float v = gaz_table[(size_t)gaz_list[b * GG + g] * DD + d];
    gat_in[((size_t)b * NN + SS + g) * DD + d] = v;
}

// ---------------------------------------------------------------------------
// BiLSTM scan.  grid 32 = (batch, dir).  256 threads, 4 waves.
// j-split: wave w computes gate partials over j in [16w,16w+16); lane u owns
// unit u (all 4 gates i,f,g,o).  Every wave then reduces the partials and
// computes the nonlinearity REDUNDANTLY (bitwise identical), so h/c stay
// consistent per-wave with no second barrier.  One barrier per step
// (double-buffered partials).  LDS/step: 4 b32 + 20 b128 vs R2's 64 b128.
// ---------------------------------------------------------------------------
__global__ __launch_bounds__(256) void k_lstm(
    const float* __restrict__ xw_f, const float* __restrict__ xw_b,
    const float* __restrict__ w_hh_f, const float* __restrict__ w_hh_b,
    float* __restrict__ gat_in)
{
    __shared__ float part[2][4][64][4];   // [buf][wave][unit][g4]
    __shared__ float hbuf[4][64];         // per-wave private copy of h
    const int tid = threadIdx.x, wv = tid >> 6, lane = tid & 63;
    const int b = blockIdx.x >> 1, dir = blockIdx.x & 1;
    const float* xw  = (dir ? xw_b : xw_f) + (size_t)b * SS * 256;
    const float* whh = dir ? w_hh_b : w_hh_f;
    // weights: gates g4*64+lane (unit=lane), j in [16*wv, 16*wv+16)
    v2f w2[4][8];
    #pragma unroll
    for (int g4 = 0; g4 < 4; ++g4) {
        const float* r = whh + (size_t)(g4 * 64 + lane) * 64 + 16 * wv;
        #pragma unroll
        for (int jj = 0; jj < 8; ++jj) w2[g4][jj] = v2f{r[2 * jj], r[2 * jj + 1]};
    }
    hbuf[wv][lane] = 0.f;                 // own-wave copy; in-order LDS
    float c = 0.f;
    int buf = 0;
    const int t0 = dir ? (SS - 1) : 0;
    float x0 = xw[t0 * 256 +   0 + lane];
    float x1 = xw[t0 * 256 +  64 + lane];
    float x2 = xw[t0 * 256 + 128 + lane];
    float x3 = xw[t0 * 256 + 192 + lane];
    const v2f* h2p = (const v2f*)&hbuf[wv][16 * wv];   // 8 v2f chunk
    for (int tt = 0; tt < SS; ++tt) {
        const int t = dir ? (SS - 1 - tt) : tt;
        const int tn = dir ? (t - 1) : (t + 1);
        // partial matvec on h(t-1): own-chunk broadcast reads (4 ds_read_b128)
        v2f a0 = v2f{0.f, 0.f}, a1 = v2f{0.f, 0.f}, a2 = v2f{0.f, 0.f}, a3 = v2f{0.f, 0.f};
        #pragma unroll
        for (int jj = 0; jj < 8; ++jj) {
            v2f hv = h2p[jj];
            a0 = __builtin_elementwise_fma(hv, w2[0][jj], a0);
            a1 = __builtin_elementwise_fma(hv, w2[1][jj], a1);
            a2 = __builtin_elementwise_fma(hv, w2[2][jj], a2);
            a3 = __builtin_elementwise_fma(hv, w2[3][jj], a3);
        }
        float4 pw;
        pw.x = a0.x + a0.y; pw.y = a1.x + a1.y;
        pw.z = a2.x + a2.y; pw.w = a3.x + a3.y;
        *(float4*)part[buf][wv][lane] = pw;
        // prefetch next step's xw gates (overlaps the barrier)
        float nx0 = 0.f, nx1 = 0.f, nx2 = 0.f, nx3 = 0.f;
        if (tt + 1 < SS) {
            nx0 = xw[tn * 256 +   0 + lane];
            nx1 = xw[tn * 256 +  64 + lane];
            nx2 = xw[tn * 256 + 128 + lane];
            nx3 = xw[tn * 256 + 192 + lane];
        }
        __syncthreads();
        float4 p0 = *(const float4*)part[buf][0][lane];
        float4 p1 = *(const float4*)part[buf][1][lane];
        float4 p2 = *(const float4*)part[buf][2][lane];
        float4 p3 = *(const float4*)part[buf][3][lane];
        float gi = ((p0.x + p1.x) + (p2.x + p3.x)) + x0;
        float gf = ((p0.y + p1.y) + (p2.y + p3.y)) + x1;
        float gg = ((p0.z + p1.z) + (p2.z + p3.z)) + x2;
        float go = ((p0.w + p1.w) + (p2.w + p3.w)) + x3;
        float nc = sigf(gf) * c + sigf(gi) * tanh_fast(gg);
        float nh = sigf(go) * tanh_fast(nc);
        c = nc;
        hbuf[wv][lane] = nh;              // own-wave copy; read next step
        if (wv == 0) gat_in[((size_t)b * NN + t) * DD + dir * 64 + lane] = nh;
        x0 = nx0; x1 = nx1; x2 = nx2; x3 = nx3;
        buf ^= 1;
    }
}

// ---------------------------------------------------------------------------
// GAT layer-1 projection: h1 = gat_in @ Wh[k][hd] (+ per-row f1/f2 dots).
// grid (192 row-tiles, 4 heads).  64x64 tile, K=128 in 2 phases of 64.
// ---------------------------------------------------------------------------
__global__ __launch_bounds__(256) void k_p1(
    const float* __restrict__ gat_in, const float* __restrict__ gat_Wh,
    const float* __restrict__ gat_ah, int k,
    float* __restrict__ h1, float* __restrict__ f1g, float* __restrict__ f2g)
{
    __shared__ float At[64 * 68];
    __shared__ float Bt[64 * 68];
    __shared__ float sf1[64], sf2[64];
    const int tid = threadIdx.x;
    const int rt = blockIdx.x, hd = blockIdx.y;
    if (tid < 64) { sf1[tid] = 0.f; sf2[tid] = 0.f; }
    const float* W = gat_Wh + ((size_t)(k * NHEADS + hd)) * DD * 64;
    const int ty = tid >> 4, tx = tid & 15;
    const int r0 = ty * 4, c0 = tx * 4;
    float acc[4][4] = {};
    for (int ph = 0; ph < 2; ++ph) {
        __syncthreads();
        for (int idx = tid; idx < 64 * 64; idx += 256) {
            int r = idx >> 6, e = idx & 63;
            At[e * 68 + r] = gat_in[((size_t)(rt * 64 + r)) * DD + ph * 64 + e];
            Bt[e * 68 + r] = W[(size_t)(ph * 64 + e) * 64 + r];
        }
        __syncthreads();
        #pragma unroll 4
        for (int e = 0; e < 64; ++e) {
            float4 a = *(const float4*)&At[e * 68 + r0];
            float4 bv = *(const float4*)&Bt[e * 68 + c0];
            float av[4] = {a.x, a.y, a.z, a.w};
            float bb[4] = {bv.x, bv.y, bv.z, bv.w};
            #pragma unroll
            for (int i = 0; i < 4; ++i)
                #pragma unroll
                for (int j = 0; j < 4; ++j) acc[i][j] = fmaf(av[i], bb[j], acc[i][j]);
        }
    }
    const float* ah = gat_ah + (size_t)(k * NHEADS + hd) * 128;
    float a1[4], a2[4];
    #pragma unroll
    for (int j = 0; j < 4; ++j) { a1[j] = ah[c0 + j]; a2[j] = ah[64 + c0 + j]; }
    #pragma unroll
    for (int i = 0; i < 4; ++i) {
        int n = rt * 64 + r0 + i;
        float4 o = make_float4(acc[i][0], acc[i][1], acc[i][2], acc[i][3]);
        *(float4*)&h1[((size_t)n * NHEADS + hd) * 64 + c0] = o;
        float p1 = acc[i][0] * a1[0] + acc[i][1] * a1[1] + acc[i][2] * a1[2] + acc[i][3] * a1[3];
        float p2 = acc[i][0] * a2[0] + acc[i][1] * a2[1] + acc[i][2] * a2[2] + acc[i][3] * a2[3];
        atomicAdd(&sf1[r0 + i], p1);
        atomicAdd(&sf2[r0 + i], p2);
    }
    __syncthreads();
    if (tid < 64) {
        f1g[hd * BN + rt * 64 + tid] = sf1[tid];
        f2g[hd * BN + rt * 64 + tid] = sf2[tid];
    }
}

// ---------------------------------------------------------------------------
// GAT layer-1 attention (sparse).  One block per row n=(b,i); wave = head.
// Ballot-based neighbor compaction (no LDS atomics); 4-acc gather.
// Also emits bit-packed adjacency for layer 2.
// ---------------------------------------------------------------------------
__global__ __launch_bounds__(256) void k_attn1(
    const int* __restrict__ adj, const float* __restrict__ h1,
    const float* __restrict__ f1g, const float* __restrict__ f2g,
    float* __restrict__ out1, unsigned long long* __restrict__ packed)
{
    __shared__ int   nbr[NN];
    __shared__ float ep[NHEADS][NN];
    __shared__ unsigned long long wm[12];
    __shared__ int cntS;
    const int tid = threadIdx.x, wave = tid >> 6, lane = tid & 63;
    const int n = blockIdx.x;
    const int b = n / NN;
    #pragma unroll
    for (int it = 0; it < 3; ++it) {
        int j = it * 256 + tid;
        int a = adj[(size_t)n * NN + j];
        unsigned long long m = __ballot(a > 0);
        if (lane == 0) { wm[it * 4 + wave] = m; packed[(size_t)n * 12 + it * 4 + wave] = m; }
    }
    __syncthreads();
    if (wave == 0) {
        unsigned long long m = (lane < 12) ? wm[lane] : 0ULL;
        int pc = __popcll(m);
        int inc = pc;
        #pragma unroll
        for (int d = 1; d < 16; d <<= 1) { int t = __shfl_up(inc, d); if (lane >= d) inc += t; }
        int C = __shfl(inc, 11);
        if (lane == 0) cntS = C;
        int off = inc - pc;
        while (m) {
            int bit = __builtin_ctzll(m);
            nbr[off++] = lane * 64 + bit;
            m &= m - 1;
        }
    }
    __syncthreads();
    const int C = cntS;
    const int hd = wave;
    const float f1 = f1g[hd * BN + n];
    const float* f2p = f2g + hd * BN + b * NN;
    float mx = -3.0e38f;
    for (int t = lane; t < C; t += 64) {
        float e = f1 + f2p[nbr[t]];
        e = (e >= 0.f) ? e : 0.2f * e;
        ep[hd][t] = e;
        mx = fmaxf(mx, e);
    }
    mx = wred_max(mx);
    float sum = 0.f;
    for (int t = lane; t < C; t += 64) {
        float p = __expf(ep[hd][t] - mx);
        ep[hd][t] = p;
        sum += p;
    }
    sum = wred_sum(sum);
    const float* hb = h1 + (size_t)b * NN * (NHEADS * 64) + hd * 64 + lane;
    float ac0 = 0.f, ac1 = 0.f, ac2 = 0.f, ac3 = 0.f;
    int t = 0;
    for (; t + 3 < C; t += 4) {
        int j0 = nbr[t], j1 = nbr[t + 1], j2 = nbr[t + 2], j3 = nbr[t + 3];
        float p0 = ep[hd][t], p1 = ep[hd][t + 1], p2 = ep[hd][t + 2], p3 = ep[hd][t + 3];
        ac0 = fmaf(p0, hb[(size_t)j0 * 256], ac0);
        ac1 = fmaf(p1, hb[(size_t)j1 * 256], ac1);
        ac2 = fmaf(p2, hb[(size_t)j2 * 256], ac2);
        ac3 = fmaf(p3, hb[(size_t)j3 * 256], ac3);
    }
    for (; t < C; ++t) ac0 = fmaf(ep[hd][t], hb[(size_t)nbr[t] * 256], ac0);
    float r = ((ac0 + ac1) + (ac2 + ac3)) / sum;
    r = (r > 0.f) ? r : expm1f(r);
    out1[(size_t)n * 256 + hd * 64 + lane] = r;
}

// ---------------------------------------------------------------------------
// Output-layer projection: h2 = out1 @ Wo[k]  (+ f1o/f2o dots).  12 rows/block.
// ---------------------------------------------------------------------------
__global__ __launch_bounds__(256) void k_p2(
    const float* __restrict__ out1, const float* __restrict__ gat_Wo,
    const float* __restrict__ gat_ao, int k,
    float* __restrict__ h2, float* __restrict__ f1o, float* __restrict__ f2o)
{
    __shared__ float ld[12 * 256];
    __shared__ float lf1[12], lf2[12];
    const int tid = threadIdx.x;
    const int blk = blockIdx.x;
    if (tid < 12) { lf1[tid] = 0.f; lf2[tid] = 0.f; }
    for (int idx = tid; idx < 12 * 256; idx += 256)
        ld[idx] = out1[(size_t)blk * 12 * 256 + idx];
    __syncthreads();
    if (tid < 252) {
        const int r = tid / TT, c = tid - r * TT;
        const float* Wo = gat_Wo + (size_t)k * 256 * TT;
        const float4* row4 = (const float4*)&ld[r * 256];
        float acc = 0.f;
        #pragma unroll 8
        for (int q4 = 0; q4 < 64; ++q4) {
            float4 v = row4[q4];
            int q = q4 * 4;
            acc = fmaf(v.x, Wo[(q + 0) * TT + c], acc);
            acc = fmaf(v.y, Wo[(q + 1) * TT + c], acc);
            acc = fmaf(v.z, Wo[(q + 2) * TT + c], acc);
            acc = fmaf(v.w, Wo[(q + 3) * TT + c], acc);
        }
        const int n = blk * 12 + r;
        h2[(size_t)n * TT + c] = acc;
        const float* ao = gat_ao + k * 2 * TT;
        atomicAdd(&lf1[r], acc * ao[c]);
        atomicAdd(&lf2[r], acc * ao[TT + c]);
    }
    __syncthreads();
    if (tid < 12) {
        f1o[blk * 12 + tid] = lf1[tid];
        f2o[blk * 12 + tid] = lf2[tid];
    }
}

// ---------------------------------------------------------------------------
// Output-layer attention + elu.  One wave per (b, s<S).  Neighbor lists are
// rebuilt from the bit-packed adjacency written by k_attn1.
// ---------------------------------------------------------------------------
__global__ __launch_bounds__(64) void k_attn2(
    const unsigned long long* __restrict__ packed,
    const float* __restrict__ h2, const float* __restrict__ f1o,
    const float* __restrict__ f2o, float* __restrict__ out2k)
{
    __shared__ int   nbr[NN];
    __shared__ float ep[NN];
    const int lane = threadIdx.x;
    const int blk = blockIdx.x;                 // b*S + s
    const int b = blk / SS, s = blk - b * SS;
    const int n = b * NN + s;
    unsigned long long w64 = (lane < 12) ? packed[(size_t)n * 12 + lane] : 0ULL;
    int pc = __popcll(w64);
    int inc = pc;
    #pragma unroll
    for (int d = 1; d < 16; d <<= 1) {
        int t = __shfl_up(inc, d, 16);
        if ((lane & 15) >= d) inc += t;
    }
    const int C = __shfl(inc, 11);
    int off = inc - pc;
    while (w64) {
        int bit = __builtin_ctzll(w64);
        nbr[off++] = lane * 64 + bit;
        w64 &= w64 - 1;
    }
    __syncthreads();
    const float f1 = f1o[n];
    const float* f2p = f2o + b * NN;
    float mx = -3.0e38f;
    for (int t = lane; t < C; t += 64) {
        int j = nbr[t];
        float e = f1 + f2p[j];
        e = (e >= 0.f) ? e : 0.2f * e;
        ep[t] = e;
        mx = fmaxf(mx, e);
    }
    mx = wred_max(mx);
    float sum = 0.f;
    for (int t = lane; t < C; t += 64) {
        float p = __expf(ep[t] - mx);
        ep[t] = p;
        sum += p;
    }
    sum = wred_sum(sum);
    const float* h2b = h2 + (size_t)b * NN * TT + ((lane < TT) ? lane : 0);
    float ac0 = 0.f, ac1 = 0.f, ac2 = 0.f, ac3 = 0.f;
    int t = 0;
    for (; t + 3 < C; t += 4) {
        int j0 = nbr[t], j1 = nbr[t + 1], j2 = nbr[t + 2], j3 = nbr[t + 3];
        float p0 = ep[t], p1 = ep[t + 1], p2 = ep[t + 2], p3 = ep[t + 3];
        ac0 = fmaf(p0, h2b[(size_t)j0 * TT], ac0);
        ac1 = fmaf(p1, h2b[(size_t)j1 * TT], ac1);
        ac2 = fmaf(p2, h2b[(size_t)j2 * TT], ac2);
        ac3 = fmaf(p3, h2b[(size_t)j3 * TT], ac3);
    }
    for (; t < C; ++t) ac0 = fmaf(ep[t], h2b[(size_t)nbr[t] * TT], ac0);
    if (lane < TT) {
        float r = ((ac0 + ac1) + (ac2 + ac3)) / sum;
        r = (r > 0.f) ? r : expm1f(r);
        out2k[(size_t)blk * TT + lane] = r;
    }
}

// ---------------------------------------------------------------------------
// feats = fuse_w[0]*(lstm_feat@h2h_W^T + b) + sum_k fuse_w[k+1]*out2_k
// ---------------------------------------------------------------------------
__global__ __launch_bounds__(64) void k_fuse(
    const float* __restrict__ gat_in, const float* __restrict__ h2h_W,
    const float* __restrict__ h2h_b, const float* __restrict__ fuse_w,
    const float* __restrict__ out2, float* __restrict__ feats)
{
    __shared__ float row[DD];
    const int lane = threadIdx.x;
    const int blk = blockIdx.x;                 // b*S + s
    const int b = blk / SS, s = blk - b * SS;
    const float* src = gat_in + ((size_t)b * NN + s) * DD;
    row[lane] = src[lane];
    row[lane + 64] = src[lane + 64];
    __syncthreads();
    if (lane < TT) {
        float acc = h2h_b[lane];
        const float4* w4 = (const float4*)&h2h_W[lane * DD];
        const float4* r4 = (const float4*)row;
        #pragma unroll 8
        for (int d4 = 0; d4 < 32; ++d4) {
            float4 w = w4[d4]; float4 v = r4[d4];
            acc = fmaf(w.x, v.x, acc); acc = fmaf(w.y, v.y, acc);
            acc = fmaf(w.z, v.z, acc); acc = fmaf(w.w, v.w, acc);
        }
        size_t o = (size_t)blk * TT + lane;
        feats[o] = fuse_w[0] * acc + fuse_w[1] * out2[o]
                 + fuse_w[2] * out2[(size_t)BS * TT + o]
                 + fuse_w[3] * out2[2 * (size_t)BS * TT + o];
    }
}

// ---------------------------------------------------------------------------
// Viterbi decode.  One wave per batch.  Lanes = (p-group 0..2) x (c 0..20).
// ---------------------------------------------------------------------------
__global__ __launch_bounds__(64) void k_vit(
    const float* __restrict__ feats, const float* __restrict__ trans,
    int* __restrict__ out)
{
    __shared__ float part[24];
    __shared__ unsigned char bp[SS - 1][24];
    const int lane = threadIdx.x;
    const int b = blockIdx.x;
    const int pg = lane / TT;                 // 0,1,2 (lane 63 idle)
    const int c = lane - pg * TT;
    const bool act = (pg < 3);
    const int p0 = pg * 7;
    float tc[7];
    if (act) {
        #pragma unroll
        for (int u = 0; u < 7; ++u) tc[u] = trans[(p0 + u) * TT + c];
    }
    if (lane < TT) part[lane] = feats[((size_t)b * SS) * TT + lane] + trans[19 * TT + lane];
    if (lane >= TT && lane < 24) part[lane] = -3.0e38f;
    __syncthreads();
    for (int t = 1; t < SS; ++t) {
        float best = -3.0e38f; int bi = 0;
        if (act) {
            #pragma unroll
            for (int u = 0; u < 7; ++u) {
                float v = part[p0 + u] + tc[u];
                if (v > best) { best = v; bi = p0 + u; }
            }
        }
        float bv1 = __shfl(best, lane + 21);
        int   bi1 = __shfl(bi,   lane + 21);
        float bv2 = __shfl(best, lane + 42);
        int   bi2 = __shfl(bi,   lane + 42);
        if (lane < TT) {
            if (bv1 > best) { best = bv1; bi = bi1; }
            if (bv2 > best) { best = bv2; bi = bi2; }
            bp[t - 1][lane] = (unsigned char)bi;
            part[lane] = best + feats[((size_t)b * SS + t) * TT + lane];
        }
        __syncthreads();
    }
    float fv = (lane < TT) ? part[lane] + trans[lane * TT + 20] : -3.0e38f;
    int fi = (lane < TT) ? lane : 0;
    #pragma unroll
    for (int o = 32; o > 0; o >>= 1) {
        float ov = __shfl_xor(fv, o);
        int oi = __shfl_xor(fi, o);
        if (ov > fv || (ov == fv && oi < fi)) { fv = ov; fi = oi; }
    }
    __syncthreads();
    if (lane == 0) {
        int cur = fi;
        out[b * SS + SS - 1] = cur;
        for (int u = SS - 2; u >= 0; --u) {
            cur = bp[u][cur];
            out[b * SS + u] = cur;
        }
    }
}

// ---------------------------------------------------------------------------
extern "C" void kernel_launch(void* const* d_in, const int* in_sizes, int n_in,
                              void* d_out, int out_size, void* d_ws, size_t ws_size,
                              hipStream_t stream) {
    (void)in_sizes; (void)n_in; (void)out_size; (void)ws_size;
    const int*   batch_char = (const int*)d_in[0];
    const int*   gaz_list   = (const int*)d_in[2];
    const int*   graphs[3]  = {(const int*)d_in[3], (const int*)d_in[4], (const int*)d_in[5]};
    const float* char_table = (const float*)d_in[7];
    const float* gaz_table  = (const float*)d_in[8];
    const float* w_ih_f = (const float*)d_in[9];
    const float* w_hh_f = (const float*)d_in[10];
    const float* b_f    = (const float*)d_in[11];
    const float* w_ih_b = (const float*)d_in[12];
    const float* w_hh_b = (const float*)d_in[13];
    const float* b_b    = (const float*)d_in[14];
    const float* h2h_W  = (const float*)d_in[15];
    const float* h2h_b  = (const float*)d_in[16];
    const float* gat_Wh = (const float*)d_in[17];
    const float* gat_ah = (const float*)d_in[18];
    const float* gat_Wo = (const float*)d_in[19];
    const float* gat_ao = (const float*)d_in[20];
    const float* fuse_w = (const float*)d_in[21];
    const float* trans  = (const float*)d_in[22];

    float* ws = (float*)d_ws;
    float* gat_in = ws;                         // 1,572,864
    float* xw_f   = gat_in + 1572864;           // 1,572,864
    float* xw_b   = xw_f   + 1572864;           // 1,572,864
    float* h1     = xw_b   + 1572864;           // 3,145,728
    float* out1   = h1     + 3145728;           // 3,145,728
    float* h2     = out1   + 3145728;           //   258,048
    float* f1g    = h2     + 258048;            //    49,152
    float* f2g    = f1g    + 49152;             //    49,152
    float* f1o    = f2g    + 49152;             //    12,288
    float* f2o    = f1o    + 12288;             //    12,288
    float* out2   = f2o    + 12288;             //   387,072
    float* feats  = out2   + 387072;            //   129,024
    unsigned long long* packed = (unsigned long long*)(feats + 129024);  // 98,304 u64

    k_xw<<<dim3(96, 8), 256, 0, stream>>>(batch_char, char_table, w_ih_f, b_f,
                                          w_ih_b, b_b, xw_f, xw_b);
    k_gaz<<<3072, 256, 0, stream>>>(gaz_list, gaz_table, gat_in);
    k_lstm<<<32, 256, 0, stream>>>(xw_f, xw_b, w_hh_f, w_hh_b, gat_in);
    for (int k = 0; k < 3; ++k) {
        k_p1<<<dim3(192, 4), 256, 0, stream>>>(gat_in, gat_Wh, gat_ah, k, h1, f1g, f2g);
        k_attn1<<<BN, 256, 0, stream>>>(graphs[k], h1, f1g, f2g, out1, packed);
        k_p2<<<1024, 256, 0, stream>>>(out1, gat_Wo, gat_ao, k, h2, f1o, f2o);
        k_attn2<<<BS, 64, 0, stream>>>(packed, h2, f1o, f2o, out2 + (size_t)k * BS * TT);
    }
    k_fuse<<<BS, 64, 0, stream>>>(gat_in, h2h_W, h2h_b, fuse_w, out2, feats);
    k_vit<<<BB, 64, 0, stream>>>(feats, trans, (int*)d_out);
}